// Round 1
// baseline (583.477 us; speedup 1.0000x reference)
//
#include <hip/hip_runtime.h>

// ---------------------------------------------------------------------------
// BitLinear: y[m][n] = sum_k x[m][k] * w[n][k]
// M=8192 (4*2048), N=4096, K=4096. x fp32, w int32 (0..255), y fp32.
// Strategy: convert x -> bf16 (RNE), w -> bf16 (exact, values fit in 8-bit
// significand), then bf16 MFMA GEMM (m97 structure: 128x128 tile, BK=32,
// 4 waves, global_load_lds width=16, XCD-bijective block swizzle).
// ---------------------------------------------------------------------------

typedef __bf16 bf16x8 __attribute__((ext_vector_type(8)));
typedef float f32x4 __attribute__((ext_vector_type(4)));
typedef unsigned short u16;
typedef u16 u16x8 __attribute__((ext_vector_type(8)));

// fp32 -> bf16 round-to-nearest-even
__device__ __forceinline__ u16 f2bf(float f) {
    unsigned int u = __builtin_bit_cast(unsigned int, f);
    u = (u + 0x7FFFu + ((u >> 16) & 1u)) >> 16;
    return (u16)u;
}

__global__ void cvt_f32_bf16_k(const float* __restrict__ in, u16* __restrict__ out, int nvec) {
    int i = blockIdx.x * blockDim.x + threadIdx.x;
    if (i >= nvec) return;
    const float4* p = (const float4*)in;
    float4 a = p[2 * i];
    float4 b = p[2 * i + 1];
    u16x8 o;
    o[0] = f2bf(a.x); o[1] = f2bf(a.y); o[2] = f2bf(a.z); o[3] = f2bf(a.w);
    o[4] = f2bf(b.x); o[5] = f2bf(b.y); o[6] = f2bf(b.z); o[7] = f2bf(b.w);
    *(u16x8*)(out + 8 * (size_t)i) = o;
}

__global__ void cvt_i32_bf16_k(const int* __restrict__ in, u16* __restrict__ out, int nvec) {
    int i = blockIdx.x * blockDim.x + threadIdx.x;
    if (i >= nvec) return;
    const int4* p = (const int4*)in;
    int4 a = p[2 * i];
    int4 b = p[2 * i + 1];
    u16x8 o;
    o[0] = f2bf((float)a.x); o[1] = f2bf((float)a.y); o[2] = f2bf((float)a.z); o[3] = f2bf((float)a.w);
    o[4] = f2bf((float)b.x); o[5] = f2bf((float)b.y); o[6] = f2bf((float)b.z); o[7] = f2bf((float)b.w);
    *(u16x8*)(out + 8 * (size_t)i) = o;
}

// async global -> LDS, 16 bytes per lane, wave-uniform LDS base
#define GLD_LDS16(gp, lp)                                                     \
    __builtin_amdgcn_global_load_lds(                                         \
        (const __attribute__((address_space(1))) void*)(gp),                  \
        (__attribute__((address_space(3))) void*)(lp), 16, 0, 0)

#define BM 128
#define BN 128
#define BK 32

// A: [M][K] bf16 row-major; B: [N][K] bf16 row-major (i.e. B^T of the GEMM);
// C: [M][N] fp32.
__global__ void gemm_bf16_bt(const u16* __restrict__ A, const u16* __restrict__ B,
                             float* __restrict__ C, int M, int N, int K) {
    __shared__ u16 As[BM * BK];  // [128][32] linear (global_load_lds needs linear dest)
    __shared__ u16 Bs[BN * BK];

    const int tid  = threadIdx.x;
    const int lane = tid & 63;
    const int wid  = tid >> 6;   // 0..3
    const int wr   = wid >> 1;   // wave row 0..1
    const int wc   = wid & 1;    // wave col 0..1

    // XCD-bijective swizzle: nwg = 2048, 2048 % 8 == 0
    const int nwg = gridDim.x;
    const int cpx = nwg >> 3;
    const int bid = blockIdx.x;
    const int swz = (bid & 7) * cpx + (bid >> 3);

    const int tiles_n = N / BN;          // 32
    const int tm = swz / tiles_n;
    const int tn = swz % tiles_n;
    const int row0 = tm * BM;
    const int col0 = tn * BN;

    // Staging: wave w covers rows [w*32, w*32+32) of each 128x32 tile, two
    // 1024B global_load_lds calls (16 rows each). Lane l -> row l/4, k-elems (l%4)*8.
    const int srow  = wid * 32 + (lane >> 2);
    const int skoff = (lane & 3) * 8;

    const u16* Ap0 = A + (size_t)(row0 + srow) * K + skoff;
    const u16* Ap1 = A + (size_t)(row0 + srow + 16) * K + skoff;
    const u16* Bp0 = B + (size_t)(col0 + srow) * K + skoff;
    const u16* Bp1 = B + (size_t)(col0 + srow + 16) * K + skoff;

    u16* As0 = &As[(wid * 32) * BK];
    u16* As1 = &As[(wid * 32 + 16) * BK];
    u16* Bs0 = &Bs[(wid * 32) * BK];
    u16* Bs1 = &Bs[(wid * 32 + 16) * BK];

    f32x4 acc[4][4] = {};

    // MFMA fragment addressing (16x16x32): A lane -> row lane&15, k (lane>>4)*8..+8
    const int fr = lane & 15;
    const int fk = (lane >> 4) * 8;

    for (int kt = 0; kt < K; kt += BK) {
        GLD_LDS16(Ap0, As0);
        GLD_LDS16(Ap1, As1);
        GLD_LDS16(Bp0, Bs0);
        GLD_LDS16(Bp1, Bs1);
        Ap0 += BK; Ap1 += BK; Bp0 += BK; Bp1 += BK;
        __syncthreads();  // drains vmcnt -> staged tile visible

        bf16x8 af[4], bfr[4];
#pragma unroll
        for (int m = 0; m < 4; ++m)
            af[m] = *(const bf16x8*)&As[(wr * 64 + m * 16 + fr) * BK + fk];
#pragma unroll
        for (int n = 0; n < 4; ++n)
            bfr[n] = *(const bf16x8*)&Bs[(wc * 64 + n * 16 + fr) * BK + fk];

#pragma unroll
        for (int m = 0; m < 4; ++m)
#pragma unroll
            for (int n = 0; n < 4; ++n)
                acc[m][n] = __builtin_amdgcn_mfma_f32_16x16x32_bf16(af[m], bfr[n], acc[m][n], 0, 0, 0);

        __syncthreads();  // all waves done reading before next staging overwrite
    }

    // C/D layout (verified m89/m91): col = lane&15, row = (lane>>4)*4 + reg
    const int crow = (lane >> 4) * 4;
    const int ccol = lane & 15;
#pragma unroll
    for (int m = 0; m < 4; ++m) {
#pragma unroll
        for (int n = 0; n < 4; ++n) {
            const size_t base = (size_t)(row0 + wr * 64 + m * 16 + crow) * N
                              + (col0 + wc * 64 + n * 16 + ccol);
#pragma unroll
            for (int r = 0; r < 4; ++r)
                C[base + (size_t)r * N] = acc[m][n][r];
        }
    }
}

extern "C" void kernel_launch(void* const* d_in, const int* in_sizes, int n_in,
                              void* d_out, int out_size, void* d_ws, size_t ws_size,
                              hipStream_t stream) {
    const float* x = (const float*)d_in[0];  // [8192][4096] fp32
    const int*   w = (const int*)d_in[1];    // [4096][4096] int32 (0..255)
    float*     out = (float*)d_out;          // [8192][4096] fp32

    const int M = 8192, N = 4096, K = 4096;

    // workspace: x_bf16 (64 MiB) then w_bf16 (32 MiB)
    u16* xb = (u16*)d_ws;
    u16* wb = xb + (size_t)M * K;

    {
        int nvec = (M * K) / 8;  // 4194304
        cvt_f32_bf16_k<<<dim3(nvec / 256), dim3(256), 0, stream>>>(x, xb, nvec);
    }
    {
        int nvec = (N * K) / 8;  // 2097152
        cvt_i32_bf16_k<<<dim3(nvec / 256), dim3(256), 0, stream>>>(w, wb, nvec);
    }

    dim3 grid((M / BM) * (N / BN));  // 64*32 = 2048
    gemm_bf16_bt<<<grid, dim3(256), 0, stream>>>(xb, wb, out, M, N, K);
}

// Round 3
// 509.907 us; speedup vs baseline: 1.1443x; 1.1443x over previous
//
#include <hip/hip_runtime.h>

// ---------------------------------------------------------------------------
// BitLinear: y[m][n] = sum_k x[m][k] * w[n][k]
// M=8192, N=4096, K=4096. x fp32, w int32 (0..255), y fp32.
// Round 2 (resubmit; round-2 bench died on GPU acquisition timeout):
// bf16 conversion prepass (fused) + 256x256 8-phase counted-vmcnt GEMM
// (T2 LDS swizzle + T3/T4 8-phase pipeline + T5 setprio).
// ---------------------------------------------------------------------------

typedef __bf16 bf16x8 __attribute__((ext_vector_type(8)));
typedef float f32x4 __attribute__((ext_vector_type(4)));
typedef unsigned short u16;
typedef u16 u16x8 __attribute__((ext_vector_type(8)));

// fp32 -> bf16 round-to-nearest-even
__device__ __forceinline__ u16 f2bf(float f) {
    unsigned int u = __builtin_bit_cast(unsigned int, f);
    u = (u + 0x7FFFu + ((u >> 16) & 1u)) >> 16;
    return (u16)u;
}

// Fused conversion: x fp32 -> bf16, w int32 -> bf16 (exact). Grid-stride.
__global__ void cvt_fused_k(const float* __restrict__ x, const int* __restrict__ w,
                            u16* __restrict__ xb, u16* __restrict__ wb,
                            int nxv, int nwv) {
    const int stride = gridDim.x * blockDim.x;
    for (int i = blockIdx.x * blockDim.x + threadIdx.x; i < nxv + nwv; i += stride) {
        if (i < nxv) {
            const float4* p = (const float4*)x;
            float4 a = p[2 * (size_t)i];
            float4 b = p[2 * (size_t)i + 1];
            u16x8 o;
            o[0] = f2bf(a.x); o[1] = f2bf(a.y); o[2] = f2bf(a.z); o[3] = f2bf(a.w);
            o[4] = f2bf(b.x); o[5] = f2bf(b.y); o[6] = f2bf(b.z); o[7] = f2bf(b.w);
            *(u16x8*)(xb + 8 * (size_t)i) = o;
        } else {
            int j = i - nxv;
            const int4* p = (const int4*)w;
            int4 a = p[2 * (size_t)j];
            int4 b = p[2 * (size_t)j + 1];
            u16x8 o;
            o[0] = f2bf((float)a.x); o[1] = f2bf((float)a.y); o[2] = f2bf((float)a.z); o[3] = f2bf((float)a.w);
            o[4] = f2bf((float)b.x); o[5] = f2bf((float)b.y); o[6] = f2bf((float)b.z); o[7] = f2bf((float)b.w);
            *(u16x8*)(wb + 8 * (size_t)j) = o;
        }
    }
}

// ---------------------------------------------------------------------------
// 256x256 8-phase GEMM.
// LDS: slab(BUF,MAT,KH) = 16KB each, 8 slabs = 128KB.
//   slab layout: [256 rows][32 elems] (64B rows), slot-swizzled:
//   logical (row, sigma) stored at slot sigma ^ (row&3)  (16B slots).
// Staging (linear dest): chunk c = wid*2+j covers rows c*16..+15; lane l
//   writes byte c*1024 + l*16 -> row c*16+(l>>2), slot l&3, so it must fetch
//   global k-slot sigma = (l&3) ^ ((l>>2)&3).
// Phase (CH,KH): 16 MFMA = C-half CH (4 m-frags) x 4 n-frags x K-half KH.
// Schedule per iteration (tiles T=2i in buf0, T+1 in buf1):
//   ph1 (b0,C0,k0) stage T+1.Ak1->b1   ph5 (b1,C0,k0) stage T+2.Ak1->b0
//   ph2 (b0,C1,k0) stage T+1.Bk1->b1   ph6 (b1,C1,k0) stage T+2.Bk1->b0
//   ph3 (b0,C0,k1) stage T+2.Ak0->b0   ph7 (b1,C0,k1) stage T+3.Ak0->b1
//   ph4 (b0,C1,k1) stage T+2.Bk0->b0   ph8 (b1,C1,k1) stage T+3.Bk0->b1
//        + vmcnt(4)                         + vmcnt(4)
// Every stage writes a slot whose last reader passed a barrier >=1 phase ago;
// each vmcnt(4) retires exactly the 8 loads of the next-needed K-tile.
// ---------------------------------------------------------------------------

#define STAGE(SBUF, SMAT, SKH, SKT)                                            \
    {                                                                          \
        const u16* gb = ((SMAT) == 0) ? Ab : Bb;                               \
        _Pragma("unroll")                                                      \
        for (int j = 0; j < 2; ++j) {                                          \
            const int c = wid * 2 + j;                                         \
            const u16* src = gb + (size_t)(c * 16 + srow) * K                  \
                             + (SKT) + (SKH) * 32 + ssig;                      \
            __builtin_amdgcn_global_load_lds(                                  \
                (const __attribute__((address_space(1))) void*)src,            \
                (__attribute__((address_space(3))) void*)(                     \
                    lds + (((SBUF) * 2 + (SMAT)) * 2 + (SKH)) * 8192 + c * 512), \
                16, 0, 0);                                                     \
        }                                                                      \
    }

#define PHASE(PBUF, CH, KH, SBUF, SMAT, SKH, SKT, DOVM)                        \
    {                                                                          \
        if ((CH) == 0) {                                                       \
            _Pragma("unroll")                                                  \
            for (int n = 0; n < 4; ++n)                                        \
                bfrag[n] = *(const bf16x8*)((const char*)lds                   \
                    + (((PBUF) * 2 + 1) * 2 + (KH)) * 16384                    \
                    + (wc * 64 + n * 16 + fr) * 64 + rd_sl);                   \
        }                                                                      \
        bf16x8 afrag[4];                                                       \
        _Pragma("unroll")                                                      \
        for (int mi = 0; mi < 4; ++mi)                                         \
            afrag[mi] = *(const bf16x8*)((const char*)lds                      \
                + (((PBUF) * 2 + 0) * 2 + (KH)) * 16384                        \
                + (wr * 128 + ((CH) * 4 + mi) * 16 + fr) * 64 + rd_sl);        \
        STAGE(SBUF, SMAT, SKH, SKT);                                           \
        if (DOVM) asm volatile("s_waitcnt vmcnt(4)" ::: "memory");             \
        asm volatile("s_barrier" ::: "memory");                                \
        __builtin_amdgcn_s_setprio(1);                                         \
        _Pragma("unroll")                                                      \
        for (int mi = 0; mi < 4; ++mi)                                         \
            _Pragma("unroll")                                                  \
            for (int n = 0; n < 4; ++n)                                        \
                acc[(CH) * 4 + mi][n] = __builtin_amdgcn_mfma_f32_16x16x32_bf16( \
                    afrag[mi], bfrag[n], acc[(CH) * 4 + mi][n], 0, 0, 0);      \
        __builtin_amdgcn_s_setprio(0);                                         \
        asm volatile("s_barrier" ::: "memory");                                \
    }

__global__ __launch_bounds__(512, 2)
void gemm_bf16_8ph(const u16* __restrict__ A, const u16* __restrict__ B,
                   float* __restrict__ C, int M, int N, int K) {
    __shared__ u16 lds[65536];  // 128 KiB

    const int tid  = threadIdx.x;
    const int lane = tid & 63;
    const int wid  = tid >> 6;   // 0..7
    const int wr   = wid >> 2;   // 0..1  (M direction)
    const int wc   = wid & 3;    // 0..3  (N direction)
    const int fr   = lane & 15;
    const int g    = lane >> 4;

    // XCD-bijective swizzle (nwg = 512, divisible by 8)
    const int nwg = gridDim.x;
    const int cpx = nwg >> 3;
    const int bid = blockIdx.x;
    const int swz = (bid & 7) * cpx + (bid >> 3);
    const int tiles_n = N / 256;           // 16
    const int row0 = (swz / tiles_n) * 256;
    const int col0 = (swz % tiles_n) * 256;

    // staging per-lane addressing
    const int srow = lane >> 2;                               // row within chunk
    const int ssig = (((lane & 3) ^ ((lane >> 2) & 3))) * 8;  // swizzled k-slot

    const u16* Ab = A + (size_t)row0 * K;
    const u16* Bb = B + (size_t)col0 * K;

    // read-side swizzled slot (bytes within 64B row)
    const int rd_sl = (g ^ (fr & 3)) << 4;

    f32x4 acc[8][4] = {};
    bf16x8 bfrag[4];

    // ---- prologue: T0 full -> buf0, T1 k0 -> buf1 ----
    STAGE(0, 0, 0, 0);
    STAGE(0, 1, 0, 0);
    STAGE(0, 0, 1, 0);
    STAGE(0, 1, 1, 0);
    STAGE(1, 0, 0, 64);
    STAGE(1, 1, 0, 64);
    asm volatile("s_waitcnt vmcnt(4)" ::: "memory");  // T0's 8 loads retired
    asm volatile("s_barrier" ::: "memory");

    const int KMASK = K - 1;  // K = 4096 (pow2); last-iter stages wrap (dead data)
    int kt = 0;
    for (int i = 0; i < K / 128; ++i) {
        const int k2 = (kt + 128) & KMASK;
        const int k3 = (kt + 192) & KMASK;
        PHASE(0, 0, 0,  1, 0, 1, kt + 64, false);
        PHASE(0, 1, 0,  1, 1, 1, kt + 64, false);
        PHASE(0, 0, 1,  0, 0, 0, k2,      false);
        PHASE(0, 1, 1,  0, 1, 0, k2,      true);
        PHASE(1, 0, 0,  0, 0, 1, k2,      false);
        PHASE(1, 1, 0,  0, 1, 1, k2,      false);
        PHASE(1, 0, 1,  1, 0, 0, k3,      false);
        PHASE(1, 1, 1,  1, 1, 0, k3,      true);
        kt += 128;
    }

    // ---- epilogue: C/D layout col=lane&15, row=(lane>>4)*4+reg (m89/m91) ----
    const int crow0 = row0 + wr * 128 + g * 4;
    const int ccol0 = col0 + wc * 64 + fr;
#pragma unroll
    for (int mf = 0; mf < 8; ++mf) {
#pragma unroll
        for (int n = 0; n < 4; ++n) {
            const size_t base = (size_t)(crow0 + mf * 16) * N + ccol0 + n * 16;
#pragma unroll
            for (int r = 0; r < 4; ++r)
                C[base + (size_t)r * N] = acc[mf][n][r];
        }
    }
}

extern "C" void kernel_launch(void* const* d_in, const int* in_sizes, int n_in,
                              void* d_out, int out_size, void* d_ws, size_t ws_size,
                              hipStream_t stream) {
    const float* x = (const float*)d_in[0];  // [8192][4096] fp32
    const int*   w = (const int*)d_in[1];    // [4096][4096] int32 (0..255)
    float*     out = (float*)d_out;          // [8192][4096] fp32

    const int M = 8192, N = 4096, K = 4096;

    u16* xb = (u16*)d_ws;                 // 64 MiB
    u16* wb = xb + (size_t)M * K;         // 32 MiB

    {
        int nxv = (M * K) / 8;  // 4194304
        int nwv = (N * K) / 8;  // 2097152
        cvt_fused_k<<<dim3(4096), dim3(256), 0, stream>>>(x, w, xb, wb, nxv, nwv);
    }

    dim3 grid((M / 256) * (N / 256));  // 32*16 = 512
    gemm_bf16_8ph<<<grid, dim3(512), 0, stream>>>(xb, wb, out, M, N, K);
}

// Round 4
// 483.474 us; speedup vs baseline: 1.2068x; 1.0547x over previous
//
#include <hip/hip_runtime.h>

// ---------------------------------------------------------------------------
// BitLinear: y[m][n] = sum_k x[m][k] * w[n][k]
// M=8192, N=4096, K=4096. x fp32, w int32 (0..255), y fp32.
// Round 4: fix LDS swizzle bit-field ((row>>1)&3, not (row&3)) -> 2-way
// (free) instead of 4-way bank aliasing on ds_read_b128. Cvt prepass: NT
// loads + integer-only bf16 round, split kernels for rocprof visibility.
// ---------------------------------------------------------------------------

typedef __bf16 bf16x8 __attribute__((ext_vector_type(8)));
typedef float f32x4 __attribute__((ext_vector_type(4)));
typedef unsigned short u16;
typedef u16 u16x8 __attribute__((ext_vector_type(8)));
typedef unsigned int u32x4 __attribute__((ext_vector_type(4)));

// fp32 bits -> bf16 bits, round-to-nearest-even (pure integer)
__device__ __forceinline__ u16 f2bf_bits(unsigned int u) {
    return (u16)((u + 0x7FFFu + ((u >> 16) & 1u)) >> 16);
}
__device__ __forceinline__ u16 i2bf(int v) {
    return f2bf_bits(__builtin_bit_cast(unsigned int, (float)v));
}

// x fp32 -> bf16. 2 vectors (64B read / 32B write) per thread.
__global__ void cvt_x_k(const float* __restrict__ x, u16* __restrict__ xb) {
    const size_t t = (size_t)blockIdx.x * blockDim.x + threadIdx.x;
    const u32x4* p = (const u32x4*)x;
#pragma unroll
    for (int v = 0; v < 2; ++v) {
        const size_t i = 2 * t + v;  // vector index (8 floats)
        u32x4 a = __builtin_nontemporal_load(&p[2 * i]);
        u32x4 b = __builtin_nontemporal_load(&p[2 * i + 1]);
        u16x8 o;
        o[0] = f2bf_bits(a[0]); o[1] = f2bf_bits(a[1]);
        o[2] = f2bf_bits(a[2]); o[3] = f2bf_bits(a[3]);
        o[4] = f2bf_bits(b[0]); o[5] = f2bf_bits(b[1]);
        o[6] = f2bf_bits(b[2]); o[7] = f2bf_bits(b[3]);
        *(u16x8*)(xb + 8 * i) = o;
    }
}

// w int32 (0..255) -> bf16 (exact). 2 vectors per thread.
__global__ void cvt_w_k(const int* __restrict__ w, u16* __restrict__ wb) {
    const size_t t = (size_t)blockIdx.x * blockDim.x + threadIdx.x;
    const u32x4* p = (const u32x4*)w;
#pragma unroll
    for (int v = 0; v < 2; ++v) {
        const size_t i = 2 * t + v;
        u32x4 a = __builtin_nontemporal_load(&p[2 * i]);
        u32x4 b = __builtin_nontemporal_load(&p[2 * i + 1]);
        u16x8 o;
        o[0] = i2bf((int)a[0]); o[1] = i2bf((int)a[1]);
        o[2] = i2bf((int)a[2]); o[3] = i2bf((int)a[3]);
        o[4] = i2bf((int)b[0]); o[5] = i2bf((int)b[1]);
        o[6] = i2bf((int)b[2]); o[7] = i2bf((int)b[3]);
        *(u16x8*)(wb + 8 * i) = o;
    }
}

// ---------------------------------------------------------------------------
// 256x256 8-phase GEMM (as round 3), with corrected T2 swizzle:
// slab [256 rows][32 elems], 64B rows, 16B slots; logical (row, sigma)
// stored at physical slot sigma ^ ((row>>1)&3).
//   store: chunk c = wid*2+j covers rows c*16..+15; lane l writes byte
//   c*1024 + l*16 -> row c*16+(l>>2), physical slot l&3, so it fetches
//   global k-slot sigma = (l&3) ^ ((l>>3)&3).
//   read: lane (g,fr) wants logical slot g at row base+fr -> physical
//   slot g ^ ((fr>>1)&3). Banks: 16*(fr&1) + 4*(g^((fr>>1)&3)) -> 8
//   distinct bank-quads per 16-lane group, 2 lanes each = free (m136).
// Schedule per iteration (tiles T=2i in buf0, T+1 in buf1):
//   ph1 (b0,C0,k0) stage T+1.Ak1->b1   ph5 (b1,C0,k0) stage T+2.Ak1->b0
//   ph2 (b0,C1,k0) stage T+1.Bk1->b1   ph6 (b1,C1,k0) stage T+2.Bk1->b0
//   ph3 (b0,C0,k1) stage T+2.Ak0->b0   ph7 (b1,C0,k1) stage T+3.Ak0->b1
//   ph4 (b0,C1,k1) stage T+2.Bk0->b0   ph8 (b1,C1,k1) stage T+3.Bk0->b1
//        + vmcnt(4)                         + vmcnt(4)
// ---------------------------------------------------------------------------

#define STAGE(SBUF, SMAT, SKH, SKT)                                            \
    {                                                                          \
        const u16* gb = ((SMAT) == 0) ? Ab : Bb;                               \
        _Pragma("unroll")                                                      \
        for (int j = 0; j < 2; ++j) {                                          \
            const int c = wid * 2 + j;                                         \
            const u16* src = gb + (size_t)(c * 16 + srow) * K                  \
                             + (SKT) + (SKH) * 32 + ssig;                      \
            __builtin_amdgcn_global_load_lds(                                  \
                (const __attribute__((address_space(1))) void*)src,            \
                (__attribute__((address_space(3))) void*)(                     \
                    lds + (((SBUF) * 2 + (SMAT)) * 2 + (SKH)) * 8192 + c * 512), \
                16, 0, 0);                                                     \
        }                                                                      \
    }

#define PHASE(PBUF, CH, KH, SBUF, SMAT, SKH, SKT, DOVM)                        \
    {                                                                          \
        if ((CH) == 0) {                                                       \
            _Pragma("unroll")                                                  \
            for (int n = 0; n < 4; ++n)                                        \
                bfrag[n] = *(const bf16x8*)((const char*)lds                   \
                    + (((PBUF) * 2 + 1) * 2 + (KH)) * 16384                    \
                    + (wc * 64 + n * 16 + fr) * 64 + rd_sl);                   \
        }                                                                      \
        bf16x8 afrag[4];                                                       \
        _Pragma("unroll")                                                      \
        for (int mi = 0; mi < 4; ++mi)                                         \
            afrag[mi] = *(const bf16x8*)((const char*)lds                      \
                + (((PBUF) * 2 + 0) * 2 + (KH)) * 16384                        \
                + (wr * 128 + ((CH) * 4 + mi) * 16 + fr) * 64 + rd_sl);        \
        STAGE(SBUF, SMAT, SKH, SKT);                                           \
        if (DOVM) asm volatile("s_waitcnt vmcnt(4)" ::: "memory");             \
        asm volatile("s_barrier" ::: "memory");                                \
        __builtin_amdgcn_s_setprio(1);                                         \
        _Pragma("unroll")                                                      \
        for (int mi = 0; mi < 4; ++mi)                                         \
            _Pragma("unroll")                                                  \
            for (int n = 0; n < 4; ++n)                                        \
                acc[(CH) * 4 + mi][n] = __builtin_amdgcn_mfma_f32_16x16x32_bf16( \
                    afrag[mi], bfrag[n], acc[(CH) * 4 + mi][n], 0, 0, 0);      \
        __builtin_amdgcn_s_setprio(0);                                         \
        asm volatile("s_barrier" ::: "memory");                                \
    }

__global__ __launch_bounds__(512, 2)
void gemm_bf16_8ph(const u16* __restrict__ A, const u16* __restrict__ B,
                   float* __restrict__ C, int M, int N, int K) {
    __shared__ u16 lds[65536];  // 128 KiB

    const int tid  = threadIdx.x;
    const int lane = tid & 63;
    const int wid  = tid >> 6;   // 0..7
    const int wr   = wid >> 2;   // 0..1  (M direction)
    const int wc   = wid & 3;    // 0..3  (N direction)
    const int fr   = lane & 15;
    const int g    = lane >> 4;

    // XCD-bijective swizzle (nwg = 512, divisible by 8)
    const int nwg = gridDim.x;
    const int cpx = nwg >> 3;
    const int bid = blockIdx.x;
    const int swz = (bid & 7) * cpx + (bid >> 3);
    const int tiles_n = N / 256;           // 16
    const int row0 = (swz / tiles_n) * 256;
    const int col0 = (swz % tiles_n) * 256;

    // staging per-lane addressing (store-side inverse of the read swizzle)
    const int srow = lane >> 2;                                   // row within chunk
    const int ssig = ((lane & 3) ^ ((lane >> 3) & 3)) * 8;        // fetched k-slot

    const u16* Ab = A + (size_t)row0 * K;
    const u16* Bb = B + (size_t)col0 * K;

    // read-side swizzled slot (bytes within 64B row)
    const int rd_sl = (g ^ ((fr >> 1) & 3)) << 4;

    f32x4 acc[8][4] = {};
    bf16x8 bfrag[4];

    // ---- prologue: T0 full -> buf0, T1 k0 -> buf1 ----
    STAGE(0, 0, 0, 0);
    STAGE(0, 1, 0, 0);
    STAGE(0, 0, 1, 0);
    STAGE(0, 1, 1, 0);
    STAGE(1, 0, 0, 64);
    STAGE(1, 1, 0, 64);
    asm volatile("s_waitcnt vmcnt(4)" ::: "memory");  // T0's 8 loads retired
    asm volatile("s_barrier" ::: "memory");

    const int KMASK = K - 1;  // K = 4096 (pow2); last-iter stages wrap (dead data)
    int kt = 0;
    for (int i = 0; i < K / 128; ++i) {
        const int k2 = (kt + 128) & KMASK;
        const int k3 = (kt + 192) & KMASK;
        PHASE(0, 0, 0,  1, 0, 1, kt + 64, false);
        PHASE(0, 1, 0,  1, 1, 1, kt + 64, false);
        PHASE(0, 0, 1,  0, 0, 0, k2,      false);
        PHASE(0, 1, 1,  0, 1, 0, k2,      true);
        PHASE(1, 0, 0,  0, 0, 1, k2,      false);
        PHASE(1, 1, 0,  0, 1, 1, k2,      false);
        PHASE(1, 0, 1,  1, 0, 0, k3,      false);
        PHASE(1, 1, 1,  1, 1, 0, k3,      true);
        kt += 128;
    }

    // ---- epilogue: C/D layout col=lane&15, row=(lane>>4)*4+reg (m89/m91) ----
    const int crow0 = row0 + wr * 128 + g * 4;
    const int ccol0 = col0 + wc * 64 + fr;
#pragma unroll
    for (int mf = 0; mf < 8; ++mf) {
#pragma unroll
        for (int n = 0; n < 4; ++n) {
            const size_t base = (size_t)(crow0 + mf * 16) * N + ccol0 + n * 16;
#pragma unroll
            for (int r = 0; r < 4; ++r)
                C[base + (size_t)r * N] = acc[mf][n][r];
        }
    }
}

extern "C" void kernel_launch(void* const* d_in, const int* in_sizes, int n_in,
                              void* d_out, int out_size, void* d_ws, size_t ws_size,
                              hipStream_t stream) {
    const float* x = (const float*)d_in[0];  // [8192][4096] fp32
    const int*   w = (const int*)d_in[1];    // [4096][4096] int32 (0..255)
    float*     out = (float*)d_out;          // [8192][4096] fp32

    const int M = 8192, N = 4096, K = 4096;

    u16* xb = (u16*)d_ws;                 // 64 MiB
    u16* wb = xb + (size_t)M * K;         // 32 MiB

    // x: 4194304 vectors = 8192 blocks * 256 threads * 2
    cvt_x_k<<<dim3(8192), dim3(256), 0, stream>>>(x, xb);
    // w: 2097152 vectors = 4096 blocks * 256 threads * 2
    cvt_w_k<<<dim3(4096), dim3(256), 0, stream>>>(w, wb);

    dim3 grid((M / 256) * (N / 256));  // 32*16 = 512
    gemm_bf16_8ph<<<grid, dim3(512), 0, stream>>>(xb, wb, out, M, N, K);
}